// Round 19
// baseline (2402.557 us; speedup 1.0000x reference)
//
#include <hip/hip_runtime.h>
#include <cmath>

namespace {
constexpr int NLc = 17;

typedef __attribute__((ext_vector_type(8))) short bf16x8;
typedef __attribute__((ext_vector_type(4))) float f32x4;

__device__ __forceinline__ float frcp(float x) { return __builtin_amdgcn_rcpf(x); }
__device__ __forceinline__ float sigm(float x) { return frcp(1.f + __expf(-x)); }
__device__ __forceinline__ float ftanh(float x) {
    float e = __expf(-2.f * fabsf(x));
    float t = (1.f - e) * frcp(1.f + e);
    return copysignf(t, x);
}

__device__ __forceinline__ unsigned short f2bf(float f) {
    union { float f; unsigned u; } v; v.f = f;
    unsigned r = v.u + 0x7FFF + ((v.u >> 16) & 1);
    return (unsigned short)(r >> 16);
}

// async global->LDS, 16B per lane; lds ptr must be wave-uniform (HW adds lane*16)
__device__ __forceinline__ void async16(void* lds_uniform, const void* gsrc) {
    __builtin_amdgcn_global_load_lds(
        (const __attribute__((address_space(1))) void*)gsrc,
        (__attribute__((address_space(3))) void*)lds_uniform,
        16, 0, 0);
}

// ---------------------------------------------------------------------------
// Prep: Wl3 = per-(GQ,kc,wave) 2KB tiles in LANE-LINEAR fragment order.
// ---------------------------------------------------------------------------
__global__ __launch_bounds__(256) void prep_lstm(
    const float* __restrict__ Whh_f, const float* __restrict__ Whh_b,
    const float* __restrict__ Wih_f, const float* __restrict__ bih_f, const float* __restrict__ bhh_f,
    const float* __restrict__ Wih_b, const float* __restrict__ bih_b, const float* __restrict__ bhh_b,
    const float* __restrict__ seg_emb,
    unsigned short* __restrict__ Wl3, float* __restrict__ projP)
{
    int idx = blockIdx.x * 256 + threadIdx.x;
    if (idx < 65536) {
        int dir = idx >> 15;
        int u = idx & 32767;
        int l  = u & 63;
        int mf = (u >> 6) & 1;
        int w  = (u >> 7) & 7;
        int kc = (u >> 10) & 7;
        int GQ = (u >> 13) & 3;
        const float* Whh = dir ? Whh_b : Whh_f;
        int g = GQ * 256 + w * 32 + mf * 16 + (l & 15);
        int q = g & 3, j = g >> 2;
        int k0 = kc * 32 + (l >> 4) * 8;
        const float* src = Whh + (size_t)(q * 256 + j) * 256 + k0;
        unsigned short* dst = Wl3 + (size_t)dir * 262144
                            + (size_t)((GQ * 8 + kc) * 8 + w) * 1024 + mf * 512 + l * 8;
        #pragma unroll
        for (int k = 0; k < 8; ++k) dst[k] = f2bf(src[k]);
    } else if (idx < 65536 + 2048) {
        int i2 = idx - 65536;
        int dir = i2 >> 10, gpp = i2 & 1023;
        int j = gpp >> 2, q = gpp & 3;
        const float* Wih = dir ? Wih_b : Wih_f;
        const float* bih = dir ? bih_b : bih_f;
        const float* bhh = dir ? bhh_b : bhh_f;
        int src = q * 256 + j;
        const float* wi = Wih + (size_t)src * 64;
        float bias = bih[src] + bhh[src];
        for (int tok = 0; tok < 3; ++tok) {
            float s = bias;
            for (int k = 0; k < 64; ++k) s += wi[k] * seg_emb[tok * 64 + k];
            projP[(dir * 3 + tok) * 1024 + gpp] = s;
        }
    }
}

// ---------------------------------------------------------------------------
// prep_gru: Wg4 fragment-linear tiles for the b-split GRU:
//   tile (w, mf, kc) at ushort off ((w*16+mf)*16+kc)*512, lane l holds
//   Wg_perm[row = w*256+mf*16+(l&15)][k = kc*32+(l>>4)*8 .. +8]
//   with row permutation g'' = 4j+q (q==3 -> zeros).
// Plus Wgi (row-major), gbhhP[4j+q], gbihP[3j+q].
// ---------------------------------------------------------------------------
__global__ __launch_bounds__(256) void prep_gru(
    const float* __restrict__ gWhh, const float* __restrict__ gbhh,
    const float* __restrict__ gWih, const float* __restrict__ gbih,
    unsigned short* __restrict__ Wg4, float* __restrict__ gbhhP,
    unsigned short* __restrict__ Wgi, float* __restrict__ gbihP)
{
    int idx = blockIdx.x * 256 + threadIdx.x;
    if (idx < 131072) {                                 // Wg4: 2048 tiles x 64 lanes
        int tile = idx >> 6, l = idx & 63;
        int w = tile >> 8, mf = (tile >> 4) & 15, kc = tile & 15;
        int row = w * 256 + mf * 16 + (l & 15);
        int q = row & 3, j = row >> 2;
        int k0 = kc * 32 + (l >> 4) * 8;
        unsigned short* dst = Wg4 + (size_t)tile * 512 + l * 8;
        if (q == 3) {
            #pragma unroll
            for (int k = 0; k < 8; ++k) dst[k] = 0;
        } else {
            const float* s = gWhh + (size_t)(q * 512 + j) * 512 + k0;
            #pragma unroll
            for (int k = 0; k < 8; ++k) dst[k] = f2bf(s[k]);
        }
    } else if (idx < 131072 + 13824) {                  // Wgi: 1536 rows x 9 chunks
        int i2 = idx - 131072;
        int row = i2 / 9, kc = i2 - row * 9;
        int j = row / 3, q = row - j * 3;
        const float* s = gWih + (size_t)(q * 512 + j) * 576 + kc * 64;
        unsigned short* dst = Wgi + (size_t)row * 576 + kc * 64;
        #pragma unroll
        for (int k = 0; k < 64; ++k) dst[k] = f2bf(s[k]);
    } else if (idx < 131072 + 13824 + 2048) {           // gbhhP
        int row = idx - 131072 - 13824;
        int j = row >> 2, q = row & 3;
        gbhhP[row] = (q == 3) ? 0.f : gbhh[q * 512 + j];
    } else if (idx < 131072 + 13824 + 2048 + 1536) {    // gbihP
        int row = idx - 131072 - 13824 - 2048;
        int j = row / 3, q = row - j * 3;
        gbihP[row] = gbih[q * 512 + j];
    }
}

// ---------------------------------------------------------------------------
// One g''-quadrant of one LSTM step (unchanged from r18).
// ---------------------------------------------------------------------------
template<int GQ>
__device__ __forceinline__ void lstm_gq(
    const unsigned short* __restrict__ W,
    unsigned short* __restrict__ myring,
    const unsigned short* hcur, unsigned short* hnxt,
    const float* projL, const int* tl, const int (&len4)[4],
    int pos, int w, int lrow, int lhi, int l, float (&c)[2][4])
{
    f32x4 acc[2][4];
    #pragma unroll
    for (int mf = 0; mf < 2; ++mf)
        #pragma unroll
        for (int nf = 0; nf < 4; ++nf) acc[mf][nf] = (f32x4){0.f, 0.f, 0.f, 0.f};

    #pragma unroll
    for (int kc = 0; kc < 8; ++kc) {
        const int slot = kc & 3;
        asm volatile("s_waitcnt vmcnt(6)" ::: "memory");
        __builtin_amdgcn_sched_barrier(0);
        bf16x8 af0 = *(const bf16x8*)(myring + slot * 1024 + l * 8);
        bf16x8 af1 = *(const bf16x8*)(myring + slot * 1024 + 512 + l * 8);
        bf16x8 bfv[4];
        #pragma unroll
        for (int nf = 0; nf < 4; ++nf)
            bfv[nf] = *(const bf16x8*)&hcur[((nf * 8 + kc) * 64 + l) * 8];
        asm volatile("s_waitcnt lgkmcnt(0)" ::: "memory");
        __builtin_amdgcn_sched_barrier(0);
        {   const int nt = (GQ * 8 + kc + 4) & 31;
            const unsigned short* src = W + (size_t)(nt * 8 + w) * 1024 + l * 8;
            async16(myring + slot * 1024,       src);
            async16(myring + slot * 1024 + 512, src + 512);
        }
        #pragma unroll
        for (int nf = 0; nf < 4; ++nf) {
            acc[0][nf] = __builtin_amdgcn_mfma_f32_16x16x32_bf16(af0, bfv[nf], acc[0][nf], 0, 0, 0);
            acc[1][nf] = __builtin_amdgcn_mfma_f32_16x16x32_bf16(af1, bfv[nf], acc[1][nf], 0, 0, 0);
        }
    }

    #pragma unroll
    for (int nf = 0; nf < 4; ++nf) {
        const int base = ((nf * 8 + GQ * 2 + (w >> 2)) * 64 + (w & 3) * 16 + lrow) * 8;
        if (pos < len4[nf]) {
            const float* pr = projL + tl[pos * 64 + nf * 16 + lrow] * 1024;
            #pragma unroll
            for (int mf = 0; mf < 2; ++mf) {
                const int j = GQ * 64 + w * 8 + mf * 4 + lhi;
                float4 pv = *(const float4*)(pr + 4 * j);
                float gi_ = acc[mf][nf][0] + pv.x;
                float gf_ = acc[mf][nf][1] + pv.y;
                float gg_ = acc[mf][nf][2] + pv.z;
                float go_ = acc[mf][nf][3] + pv.w;
                float cn = sigm(gf_) * c[mf][nf] + sigm(gi_) * ftanh(gg_);
                c[mf][nf] = cn;
                hnxt[base + mf * 4 + lhi] = f2bf(sigm(go_) * ftanh(cn));
            }
        } else {
            #pragma unroll
            for (int mf = 0; mf < 2; ++mf)
                hnxt[base + mf * 4 + lhi] = hcur[base + mf * 4 + lhi];  // frozen
        }
    }
}

// ---------------------------------------------------------------------------
// Fully-fused LSTM; final h written directly into GRU input layout
// x[t*256 + b][dir*256 + j]  (unchanged from r18).
// ---------------------------------------------------------------------------
__global__ __launch_bounds__(512) void lstm_fused(
    const unsigned short* __restrict__ Wl3, const float* __restrict__ projP,
    const int* __restrict__ tokens, const int* __restrict__ seg_lens,
    unsigned short* __restrict__ xbuf)
{
    __shared__ __align__(16) unsigned short hl[2][16384];      // 64 KB
    __shared__ __align__(16) unsigned short wring[8][4 * 1024];// 64 KB
    __shared__ __align__(16) float projL[3072];                // 12 KB
    __shared__ int tl[1024];                                   // 4 KB [pos][nloc]
    const int dir = blockIdx.y;
    const int n0 = blockIdx.x * 64;
    const unsigned short* W = Wl3 + (size_t)dir * 262144;

    const int tid = threadIdx.x;
    const int w = tid >> 6, l = tid & 63;
    const int lrow = l & 15, lhi = l >> 4;

    for (int i = tid; i < 2048; i += 512)
        *(uint4*)&hl[0][i * 8] = make_uint4(0, 0, 0, 0);
    for (int i = tid; i < 1024; i += 512)
        tl[(i & 15) * 64 + (i >> 4)] = tokens[n0 * 16 + i];    // transpose-stage
    for (int i = tid; i < 3072; i += 512)
        projL[i] = projP[dir * 3072 + i];
    int len4[4];
    #pragma unroll
    for (int nf = 0; nf < 4; ++nf) len4[nf] = seg_lens[n0 + nf * 16 + lrow];
    __syncthreads();

    unsigned short* myring = wring[w];
    #pragma unroll
    for (int t = 0; t < 4; ++t) {
        const unsigned short* src = W + (size_t)(t * 8 + w) * 1024 + l * 8;
        async16(myring + t * 1024,       src);
        async16(myring + t * 1024 + 512, src + 512);
    }

    float c0[2][4] = {}, c1[2][4] = {}, c2[2][4] = {}, c3[2][4] = {};
    unsigned short* hcur = hl[0];
    unsigned short* hnxt = hl[1];
    for (int s = 0; s < 16; ++s) {
        const int pos = dir ? (15 - s) : s;
        lstm_gq<0>(W, myring, hcur, hnxt, projL, tl, len4, pos, w, lrow, lhi, l, c0);
        lstm_gq<1>(W, myring, hcur, hnxt, projL, tl, len4, pos, w, lrow, lhi, l, c1);
        lstm_gq<2>(W, myring, hcur, hnxt, projL, tl, len4, pos, w, lrow, lhi, l, c2);
        lstm_gq<3>(W, myring, hcur, hnxt, projL, tl, len4, pos, w, lrow, lhi, l, c3);
        __syncthreads();
        unsigned short* t2 = hcur; hcur = hnxt; hnxt = t2;
    }

    for (int i = tid; i < 2048; i += 512) {
        int row = i >> 5, chunk = i & 31;
        *(uint4*)&xbuf[((size_t)(row * 256 + blockIdx.x)) * 576 + dir * 256 + chunk * 8] =
            *(const uint4*)&hcur[(((row >> 4) * 8 + (chunk >> 2)) * 64
                                  + (chunk & 3) * 16 + (row & 15)) * 8];
    }
}

// ---------------------------------------------------------------------------
// build_x_lab: fill x[np][512..575] = bf16(lab_emb[prev]) only.
// ---------------------------------------------------------------------------
__global__ __launch_bounds__(256) void build_x_lab(
    const float* __restrict__ lab_emb, const int* __restrict__ labels,
    unsigned short* __restrict__ x)
{
    int idx = blockIdx.x * 256 + threadIdx.x;   // 16384*32 total
    int np = idx >> 5, wd = idx & 31;
    int t = np >> 8, b = np & 255;
    int n = b * 64 + t;
    int prev = (t == 0) ? NLc : labels[n - 1];
    float2 lv = *(const float2*)&lab_emb[prev * 64 + wd * 2];
    ((unsigned*)(x + (size_t)np * 576 + 512))[wd] =
        (unsigned)f2bf(lv.x) | ((unsigned)f2bf(lv.y) << 16);
}

// ---------------------------------------------------------------------------
// gi GEMM (one 32-t half): giC[3j+q][np] = sum_k Wgi[3j+q][k]*x[np][k] + b
// ---------------------------------------------------------------------------
__global__ __launch_bounds__(256) void gi_gemm(
    const unsigned short* __restrict__ Wgi, const unsigned short* __restrict__ x,
    const float* __restrict__ gbihP, float* __restrict__ giC)
{
    __shared__ __align__(16) char smem[16384];
    const int n0 = blockIdx.x * 128;
    const int g0 = blockIdx.y * 128;
    const int tid = threadIdx.x;
    const int w = tid >> 6, l = tid & 63;
    const int wm = w & 1, wn = w >> 1;
    const int lrow = l & 15, lkb = (l >> 4) * 16;

    f32x4 acc[4][4];
    #pragma unroll
    for (int mf = 0; mf < 4; ++mf)
        #pragma unroll
        for (int nf = 0; nf < 4; ++nf)
            acc[mf][nf] = (f32x4){0.f, 0.f, 0.f, 0.f};

    for (int it = 0; it < 18; ++it) {
        const int k0 = it * 32;
        #pragma unroll
        for (int rr = 0; rr < 2; ++rr) {
            const int off = (rr * 4 + w) * 1024;
            const int row = (off + l * 16) >> 6;
            const int kb  = (off + l * 16) & 63;
            async16(smem + off,        (const char*)(Wgi + (size_t)(g0 + row) * 576 + k0) + kb);
            async16(smem + 8192 + off, (const char*)(x   + (size_t)(n0 + row) * 576 + k0) + kb);
        }
        __syncthreads();
        bf16x8 af[4], bfv[4];
        #pragma unroll
        for (int mf = 0; mf < 4; ++mf)
            af[mf] = *(const bf16x8*)(smem + ((wm * 64 + mf * 16 + lrow) * 64 + lkb));
        #pragma unroll
        for (int nf = 0; nf < 4; ++nf)
            bfv[nf] = *(const bf16x8*)(smem + 8192 + ((wn * 64 + nf * 16 + lrow) * 64 + lkb));
        #pragma unroll
        for (int mf = 0; mf < 4; ++mf)
            #pragma unroll
            for (int nf = 0; nf < 4; ++nf)
                acc[mf][nf] = __builtin_amdgcn_mfma_f32_16x16x32_bf16(af[mf], bfv[nf], acc[mf][nf], 0, 0, 0);
        __syncthreads();
    }
    #pragma unroll
    for (int mf = 0; mf < 4; ++mf) {
        const int rbase = g0 + wm * 64 + mf * 16 + (l >> 4) * 4;
        const float* bq = gbihP + rbase;
        #pragma unroll
        for (int nf = 0; nf < 4; ++nf) {
            const int np = n0 + wn * 64 + nf * 16 + lrow;
            #pragma unroll
            for (int reg = 0; reg < 4; ++reg)
                giC[(size_t)(rbase + reg) * 8192 + np] = acc[mf][nf][reg] + bq[reg];
        }
    }
}

// ---------------------------------------------------------------------------
// GRU b-split: 16 INDEPENDENT blocks x 16 batch rows, 32 steps/launch, NO
// inter-block sync (recurrence couples j within a row, never across b).
// Per step: gates^T[4j+q][b16] = Wg.h  (M=2048,N=16,K=512; 2048 MFMAs).
// W streamed via wave-private LDS ring (r11 pattern); h bf16 fragment-linear
// in LDS dbuf; per-thread h_prev f32 in regs. Cross-launch carry via hsT.
// Phase p = kc*8+ip (128/step): slot = ip&3, prefetch tile (p+4)&127.
// ---------------------------------------------------------------------------
__global__ __launch_bounds__(512) void gru_bsplit(
    const unsigned short* __restrict__ Wg4, const float* __restrict__ giC,
    const float* __restrict__ gbhhP, float* __restrict__ hsT, int tbase)
{
    __shared__ __align__(16) unsigned short wring[8][4 * 1024];  // 64 KB
    __shared__ __align__(16) unsigned short hfl[2][8192];        // 32 KB
    const int B0 = blockIdx.x * 16;
    const int tid = threadIdx.x;
    const int w = tid >> 6, l = tid & 63;
    const int lrow = l & 15, lhi = l >> 4;
    const unsigned short* W4 = Wg4 + (size_t)w * (16 * 16 * 512);  // this wave's slice

    // h_prev (f32) for this thread's 16 (j, b=lrow) outputs; carry via hsT.
    float hp[16];
    #pragma unroll
    for (int mf = 0; mf < 16; ++mf) {
        if (tbase == 0) hp[mf] = 0.f;
        else {
            const int j = w * 64 + mf * 4 + lhi;
            hp[mf] = hsT[(size_t)tbase * 131072 + (size_t)j * 256 + B0 + lrow];
        }
    }
    // hfl[0] = bf16(h_{tbase}) at fragment-linear positions (full coverage).
    #pragma unroll
    for (int mf = 0; mf < 16; ++mf) {
        const int kcp = w * 2 + (mf >> 3);
        const int lanep = ((mf >> 1) & 3) * 16 + lrow;
        const int e = (mf & 1) * 4 + lhi;
        hfl[0][(kcp * 64 + lanep) * 8 + e] = f2bf(hp[mf]);
    }
    __syncthreads();   // drains hp loads + hfl writes -> clean vmcnt for ring

    unsigned short* myring = wring[w];
    #pragma unroll
    for (int s = 0; s < 4; ++s) {      // prologue: tiles (kc=0, ip=0..3)
        async16(myring + s * 1024,       W4 + (size_t)((2 * s) * 16) * 512 + l * 8);
        async16(myring + s * 1024 + 512, W4 + (size_t)((2 * s + 1) * 16) * 512 + l * 8);
    }

    unsigned short* hcur = hfl[0];
    unsigned short* hnxt = hfl[1];

    for (int tl = 0; tl < 32; ++tl) {
        const int t = tbase + tl;

        f32x4 acc[16];
        #pragma unroll
        for (int mf = 0; mf < 16; ++mf) acc[mf] = (f32x4){0.f, 0.f, 0.f, 0.f};

        for (int kc = 0; kc < 16; ++kc) {
            bf16x8 bfv;
            #pragma unroll
            for (int ip = 0; ip < 8; ++ip) {
                const int slot = ip & 3;
                asm volatile("s_waitcnt vmcnt(6)" ::: "memory");
                __builtin_amdgcn_sched_barrier(0);
                bf16x8 af0 = *(const bf16x8*)(myring + slot * 1024 + l * 8);
                bf16x8 af1 = *(const bf16x8*)(myring + slot * 1024 + 512 + l * 8);
                if (ip == 0) bfv = *(const bf16x8*)&hcur[kc * 512 + l * 8];
                asm volatile("s_waitcnt lgkmcnt(0)" ::: "memory");
                __builtin_amdgcn_sched_barrier(0);
                {   // prefetch tile (p+4) & 127 into the slot just consumed
                    const int np = (kc * 8 + ip + 4) & 127;
                    const int nkc = np >> 3, nip = np & 7;
                    async16(myring + slot * 1024,
                            W4 + (size_t)((2 * nip) * 16 + nkc) * 512 + l * 8);
                    async16(myring + slot * 1024 + 512,
                            W4 + (size_t)((2 * nip + 1) * 16 + nkc) * 512 + l * 8);
                }
                acc[2 * ip]     = __builtin_amdgcn_mfma_f32_16x16x32_bf16(af0, bfv, acc[2 * ip], 0, 0, 0);
                acc[2 * ip + 1] = __builtin_amdgcn_mfma_f32_16x16x32_bf16(af1, bfv, acc[2 * ip + 1], 0, 0, 0);
            }
        }

        // epilogue: cell update, lane-local gates (q = acc reg: r,z,n,pad)
        #pragma unroll
        for (int mf = 0; mf < 16; ++mf) {
            const int j = w * 64 + mf * 4 + lhi;
            const int col = tl * 256 + B0 + lrow;
            float gir = giC[(size_t)(3 * j + 0) * 8192 + col];
            float giz = giC[(size_t)(3 * j + 1) * 8192 + col];
            float gin = giC[(size_t)(3 * j + 2) * 8192 + col];
            float4 bq = *(const float4*)(gbhhP + 4 * j);
            float r = sigm(gir + acc[mf][0] + bq.x);
            float z = sigm(giz + acc[mf][1] + bq.y);
            float ng = ftanh(gin + r * (acc[mf][2] + bq.z));
            float hn = (1.f - z) * ng + z * hp[mf];
            hp[mf] = hn;
            hsT[(size_t)(t + 1) * 131072 + (size_t)j * 256 + B0 + lrow] = hn;
            const int kcp = w * 2 + (mf >> 3);
            const int lanep = ((mf >> 1) & 3) * 16 + lrow;
            const int e = (mf & 1) * 4 + lhi;
            hnxt[(kcp * 64 + lanep) * 8 + e] = f2bf(hn);
        }
        __syncthreads();   // hnxt complete before next step's reads
        unsigned short* t2 = hcur; hcur = hnxt; hnxt = t2;
    }
}

// ---------------------------------------------------------------------------
// logits: block per t, 512 threads = (b, j-half); LDS partial reduce.
// ---------------------------------------------------------------------------
__global__ __launch_bounds__(512) void logits_k(
    const float* __restrict__ hsT, const float* __restrict__ Wout,
    const float* __restrict__ bout, float* __restrict__ out)
{
    __shared__ float red[2][256][17];   // 34.8 KB
    const int t = blockIdx.x;
    const int tid = threadIdx.x;
    const int b = tid & 255, js = tid >> 8;
    const float* h = hsT + (size_t)(t + 1) * 131072;
    float acc[17];
    #pragma unroll
    for (int l2 = 0; l2 < 17; ++l2) acc[l2] = 0.f;
    for (int j = js * 256; j < js * 256 + 256; ++j) {
        float hv = h[j * 256 + b];
        #pragma unroll
        for (int l2 = 0; l2 < 17; ++l2) acc[l2] += hv * Wout[l2 * 512 + j];
    }
    #pragma unroll
    for (int l2 = 0; l2 < 17; ++l2) red[js][b][l2] = acc[l2];
    __syncthreads();
    for (int o = tid; o < 256 * 17; o += 512) {
        int bb = o / 17, l2 = o - bb * 17;
        out[((size_t)bb * 64 + t) * 17 + l2] =
            red[0][bb][l2] + red[1][bb][l2] + bout[l2];
    }
}

} // namespace

extern "C" void kernel_launch(void* const* d_in, const int* in_sizes, int n_in,
                              void* d_out, int out_size, void* d_ws, size_t ws_size,
                              hipStream_t stream)
{
    const int*   tokens   = (const int*)d_in[0];
    const int*   seg_lens = (const int*)d_in[1];
    const int*   labels   = (const int*)d_in[2];
    const float* seg_emb  = (const float*)d_in[3];
    const float* Wih_f    = (const float*)d_in[4];
    const float* Whh_f    = (const float*)d_in[5];
    const float* bih_f    = (const float*)d_in[6];
    const float* bhh_f    = (const float*)d_in[7];
    const float* Wih_b    = (const float*)d_in[8];
    const float* Whh_b    = (const float*)d_in[9];
    const float* bih_b    = (const float*)d_in[10];
    const float* bhh_b    = (const float*)d_in[11];
    const float* lab_emb  = (const float*)d_in[12];
    const float* gWih     = (const float*)d_in[13];
    const float* gWhh     = (const float*)d_in[14];
    const float* gbih     = (const float*)d_in[15];
    const float* gbhh     = (const float*)d_in[16];
    const float* Wout     = (const float*)d_in[17];
    const float* bout     = (const float*)d_in[18];
    float* out = (float*)d_out;

    // Workspace ~102 MiB. All buffers fully written before read -> no memsets.
    char* p = (char*)d_ws;
    auto take = [&](size_t bytes) { char* r = p; p += (bytes + 255) & ~size_t(255); return r; };
    unsigned short* Wl   = (unsigned short*)take((size_t)2 * 1024 * 256 * 2);    // Wl3 tiles
    float*          projP= (float*)take((size_t)2 * 3 * 1024 * 4);
    unsigned short* Wg4  = (unsigned short*)take((size_t)2048 * 512 * 2);        // frag tiles
    float*          gbhhP= (float*)take((size_t)2048 * 4);
    unsigned short* Wgi  = (unsigned short*)take((size_t)1536 * 576 * 2);
    float*          gbihP= (float*)take((size_t)1536 * 4);
    unsigned short* xbuf = (unsigned short*)take((size_t)16384 * 576 * 2);   // 18 MiB
    float*          hsT  = (float*)take((size_t)65 * 512 * 256 * 4);         // 32.5 MiB
    float*          giC  = (float*)take((size_t)1536 * 8192 * 4);            // 48 MiB

    prep_lstm<<<264, 256, 0, stream>>>(Whh_f, Whh_b, Wih_f, bih_f, bhh_f,
                                       Wih_b, bih_b, bhh_b, seg_emb, Wl, projP);
    prep_gru<<<580, 256, 0, stream>>>(gWhh, gbhh, gWih, gbih, Wg4, gbhhP, Wgi, gbihP);

    lstm_fused<<<dim3(256, 2), 512, 0, stream>>>(Wl, projP, tokens, seg_lens, xbuf);

    build_x_lab<<<2048, 256, 0, stream>>>(lab_emb, labels, xbuf);

    for (int half = 0; half < 2; ++half) {
        gi_gemm<<<dim3(64, 12), 256, 0, stream>>>(
            Wgi, xbuf + (size_t)half * 8192 * 576, gbihP, giC);
        gru_bsplit<<<16, 512, 0, stream>>>(Wg4, giC, gbhhP, hsT, half * 32);
    }

    logits_k<<<64, 512, 0, stream>>>(hsT, Wout, bout, out);
}

// Round 20
// 1410.213 us; speedup vs baseline: 1.7037x; 1.7037x over previous
//
#include <hip/hip_runtime.h>
#include <cmath>

namespace {
constexpr int NLc = 17;

typedef __attribute__((ext_vector_type(8))) short bf16x8;
typedef __attribute__((ext_vector_type(4))) float f32x4;

__device__ __forceinline__ float frcp(float x) { return __builtin_amdgcn_rcpf(x); }
__device__ __forceinline__ float sigm(float x) { return frcp(1.f + __expf(-x)); }
__device__ __forceinline__ float ftanh(float x) {
    float e = __expf(-2.f * fabsf(x));
    float t = (1.f - e) * frcp(1.f + e);
    return copysignf(t, x);
}

__device__ __forceinline__ unsigned short f2bf(float f) {
    union { float f; unsigned u; } v; v.f = f;
    unsigned r = v.u + 0x7FFF + ((v.u >> 16) & 1);
    return (unsigned short)(r >> 16);
}
__device__ __forceinline__ float bf2f(unsigned short s) {
    union { unsigned u; float f; } v; v.u = (unsigned)s << 16;
    return v.f;
}

// async global->LDS, 16B per lane; lds ptr must be wave-uniform (HW adds lane*16)
__device__ __forceinline__ void async16(void* lds_uniform, const void* gsrc) {
    __builtin_amdgcn_global_load_lds(
        (const __attribute__((address_space(1))) void*)gsrc,
        (__attribute__((address_space(3))) void*)lds_uniform,
        16, 0, 0);
}

// ---------------------------------------------------------------------------
// Prep: Wl3 = per-(GQ,kc,wave) 2KB tiles in LANE-LINEAR fragment order.
// ---------------------------------------------------------------------------
__global__ __launch_bounds__(256) void prep_lstm(
    const float* __restrict__ Whh_f, const float* __restrict__ Whh_b,
    const float* __restrict__ Wih_f, const float* __restrict__ bih_f, const float* __restrict__ bhh_f,
    const float* __restrict__ Wih_b, const float* __restrict__ bih_b, const float* __restrict__ bhh_b,
    const float* __restrict__ seg_emb,
    unsigned short* __restrict__ Wl3, float* __restrict__ projP)
{
    int idx = blockIdx.x * 256 + threadIdx.x;
    if (idx < 65536) {
        int dir = idx >> 15;
        int u = idx & 32767;
        int l  = u & 63;
        int mf = (u >> 6) & 1;
        int w  = (u >> 7) & 7;
        int kc = (u >> 10) & 7;
        int GQ = (u >> 13) & 3;
        const float* Whh = dir ? Whh_b : Whh_f;
        int g = GQ * 256 + w * 32 + mf * 16 + (l & 15);
        int q = g & 3, j = g >> 2;
        int k0 = kc * 32 + (l >> 4) * 8;
        const float* src = Whh + (size_t)(q * 256 + j) * 256 + k0;
        unsigned short* dst = Wl3 + (size_t)dir * 262144
                            + (size_t)((GQ * 8 + kc) * 8 + w) * 1024 + mf * 512 + l * 8;
        #pragma unroll
        for (int k = 0; k < 8; ++k) dst[k] = f2bf(src[k]);
    } else if (idx < 65536 + 2048) {
        int i2 = idx - 65536;
        int dir = i2 >> 10, gpp = i2 & 1023;
        int j = gpp >> 2, q = gpp & 3;
        const float* Wih = dir ? Wih_b : Wih_f;
        const float* bih = dir ? bih_b : bih_f;
        const float* bhh = dir ? bhh_b : bhh_f;
        int src = q * 256 + j;
        const float* wi = Wih + (size_t)src * 64;
        float bias = bih[src] + bhh[src];
        for (int tok = 0; tok < 3; ++tok) {
            float s = bias;
            for (int k = 0; k < 64; ++k) s += wi[k] * seg_emb[tok * 64 + k];
            projP[(dir * 3 + tok) * 1024 + gpp] = s;
        }
    }
}

// Wg[4j+q][k] (q==3 -> 0); gbhhP[4j+q]; Wgi[3j+q][k]; gbihP[3j+q]  (chunked)
__global__ __launch_bounds__(256) void prep_gru(
    const float* __restrict__ gWhh, const float* __restrict__ gbhh,
    const float* __restrict__ gWih, const float* __restrict__ gbih,
    unsigned short* __restrict__ Wg, float* __restrict__ gbhhP,
    unsigned short* __restrict__ Wgi, float* __restrict__ gbihP)
{
    int idx = blockIdx.x * 256 + threadIdx.x;
    if (idx < 16384) {                                  // Wg: 2048 rows x 8 chunks
        int row = idx >> 3, kc = idx & 7;
        int j = row >> 2, q = row & 3;
        unsigned short* dst = Wg + (size_t)row * 512 + kc * 64;
        if (q == 3) {
            #pragma unroll
            for (int k = 0; k < 64; ++k) dst[k] = 0;
        } else {
            const float* s = gWhh + (size_t)(q * 512 + j) * 512 + kc * 64;
            #pragma unroll
            for (int k = 0; k < 64; ++k) dst[k] = f2bf(s[k]);
        }
    } else if (idx < 16384 + 13824) {                   // Wgi: 1536 rows x 9 chunks
        int i2 = idx - 16384;
        int row = i2 / 9, kc = i2 - row * 9;
        int j = row / 3, q = row - j * 3;
        const float* s = gWih + (size_t)(q * 512 + j) * 576 + kc * 64;
        unsigned short* dst = Wgi + (size_t)row * 576 + kc * 64;
        #pragma unroll
        for (int k = 0; k < 64; ++k) dst[k] = f2bf(s[k]);
    } else if (idx < 16384 + 13824 + 2048) {            // gbhhP
        int row = idx - 16384 - 13824;
        int j = row >> 2, q = row & 3;
        gbhhP[row] = (q == 3) ? 0.f : gbhh[q * 512 + j];
    } else if (idx < 16384 + 13824 + 2048 + 1536) {     // gbihP
        int row = idx - 16384 - 13824 - 2048;
        int j = row / 3, q = row - j * 3;
        gbihP[row] = gbih[q * 512 + j];
    }
}

// ---------------------------------------------------------------------------
// One g''-quadrant of one LSTM step (r18-proven).
// ---------------------------------------------------------------------------
template<int GQ>
__device__ __forceinline__ void lstm_gq(
    const unsigned short* __restrict__ W,
    unsigned short* __restrict__ myring,
    const unsigned short* hcur, unsigned short* hnxt,
    const float* projL, const int* tl, const int (&len4)[4],
    int pos, int w, int lrow, int lhi, int l, float (&c)[2][4])
{
    f32x4 acc[2][4];
    #pragma unroll
    for (int mf = 0; mf < 2; ++mf)
        #pragma unroll
        for (int nf = 0; nf < 4; ++nf) acc[mf][nf] = (f32x4){0.f, 0.f, 0.f, 0.f};

    #pragma unroll
    for (int kc = 0; kc < 8; ++kc) {
        const int slot = kc & 3;
        asm volatile("s_waitcnt vmcnt(6)" ::: "memory");
        __builtin_amdgcn_sched_barrier(0);
        bf16x8 af0 = *(const bf16x8*)(myring + slot * 1024 + l * 8);
        bf16x8 af1 = *(const bf16x8*)(myring + slot * 1024 + 512 + l * 8);
        bf16x8 bfv[4];
        #pragma unroll
        for (int nf = 0; nf < 4; ++nf)
            bfv[nf] = *(const bf16x8*)&hcur[((nf * 8 + kc) * 64 + l) * 8];
        asm volatile("s_waitcnt lgkmcnt(0)" ::: "memory");
        __builtin_amdgcn_sched_barrier(0);
        {   const int nt = (GQ * 8 + kc + 4) & 31;
            const unsigned short* src = W + (size_t)(nt * 8 + w) * 1024 + l * 8;
            async16(myring + slot * 1024,       src);
            async16(myring + slot * 1024 + 512, src + 512);
        }
        #pragma unroll
        for (int nf = 0; nf < 4; ++nf) {
            acc[0][nf] = __builtin_amdgcn_mfma_f32_16x16x32_bf16(af0, bfv[nf], acc[0][nf], 0, 0, 0);
            acc[1][nf] = __builtin_amdgcn_mfma_f32_16x16x32_bf16(af1, bfv[nf], acc[1][nf], 0, 0, 0);
        }
    }

    #pragma unroll
    for (int nf = 0; nf < 4; ++nf) {
        const int base = ((nf * 8 + GQ * 2 + (w >> 2)) * 64 + (w & 3) * 16 + lrow) * 8;
        if (pos < len4[nf]) {
            const float* pr = projL + tl[pos * 64 + nf * 16 + lrow] * 1024;
            #pragma unroll
            for (int mf = 0; mf < 2; ++mf) {
                const int j = GQ * 64 + w * 8 + mf * 4 + lhi;
                float4 pv = *(const float4*)(pr + 4 * j);
                float gi_ = acc[mf][nf][0] + pv.x;
                float gf_ = acc[mf][nf][1] + pv.y;
                float gg_ = acc[mf][nf][2] + pv.z;
                float go_ = acc[mf][nf][3] + pv.w;
                float cn = sigm(gf_) * c[mf][nf] + sigm(gi_) * ftanh(gg_);
                c[mf][nf] = cn;
                hnxt[base + mf * 4 + lhi] = f2bf(sigm(go_) * ftanh(cn));
            }
        } else {
            #pragma unroll
            for (int mf = 0; mf < 2; ++mf)
                hnxt[base + mf * 4 + lhi] = hcur[base + mf * 4 + lhi];  // frozen
        }
    }
}

// ---------------------------------------------------------------------------
// Fully-fused LSTM; final h written directly into GRU input layout
// x[t*256 + b][dir*256 + j]  (r18-proven).
// ---------------------------------------------------------------------------
__global__ __launch_bounds__(512) void lstm_fused(
    const unsigned short* __restrict__ Wl3, const float* __restrict__ projP,
    const int* __restrict__ tokens, const int* __restrict__ seg_lens,
    unsigned short* __restrict__ xbuf)
{
    __shared__ __align__(16) unsigned short hl[2][16384];      // 64 KB
    __shared__ __align__(16) unsigned short wring[8][4 * 1024];// 64 KB
    __shared__ __align__(16) float projL[3072];                // 12 KB
    __shared__ int tl[1024];                                   // 4 KB [pos][nloc]
    const int dir = blockIdx.y;
    const int n0 = blockIdx.x * 64;
    const unsigned short* W = Wl3 + (size_t)dir * 262144;

    const int tid = threadIdx.x;
    const int w = tid >> 6, l = tid & 63;
    const int lrow = l & 15, lhi = l >> 4;

    for (int i = tid; i < 2048; i += 512)
        *(uint4*)&hl[0][i * 8] = make_uint4(0, 0, 0, 0);
    for (int i = tid; i < 1024; i += 512)
        tl[(i & 15) * 64 + (i >> 4)] = tokens[n0 * 16 + i];    // transpose-stage
    for (int i = tid; i < 3072; i += 512)
        projL[i] = projP[dir * 3072 + i];
    int len4[4];
    #pragma unroll
    for (int nf = 0; nf < 4; ++nf) len4[nf] = seg_lens[n0 + nf * 16 + lrow];
    __syncthreads();

    unsigned short* myring = wring[w];
    #pragma unroll
    for (int t = 0; t < 4; ++t) {
        const unsigned short* src = W + (size_t)(t * 8 + w) * 1024 + l * 8;
        async16(myring + t * 1024,       src);
        async16(myring + t * 1024 + 512, src + 512);
    }

    float c0[2][4] = {}, c1[2][4] = {}, c2[2][4] = {}, c3[2][4] = {};
    unsigned short* hcur = hl[0];
    unsigned short* hnxt = hl[1];
    for (int s = 0; s < 16; ++s) {
        const int pos = dir ? (15 - s) : s;
        lstm_gq<0>(W, myring, hcur, hnxt, projL, tl, len4, pos, w, lrow, lhi, l, c0);
        lstm_gq<1>(W, myring, hcur, hnxt, projL, tl, len4, pos, w, lrow, lhi, l, c1);
        lstm_gq<2>(W, myring, hcur, hnxt, projL, tl, len4, pos, w, lrow, lhi, l, c2);
        lstm_gq<3>(W, myring, hcur, hnxt, projL, tl, len4, pos, w, lrow, lhi, l, c3);
        __syncthreads();
        unsigned short* t2 = hcur; hcur = hnxt; hnxt = t2;
    }

    for (int i = tid; i < 2048; i += 512) {
        int row = i >> 5, chunk = i & 31;
        *(uint4*)&xbuf[((size_t)(row * 256 + blockIdx.x)) * 576 + dir * 256 + chunk * 8] =
            *(const uint4*)&hcur[(((row >> 4) * 8 + (chunk >> 2)) * 64
                                  + (chunk & 3) * 16 + (row & 15)) * 8];
    }
}

// ---------------------------------------------------------------------------
// build_x_lab: fill x[np][512..575] = bf16(lab_emb[prev]) only.
// ---------------------------------------------------------------------------
__global__ __launch_bounds__(256) void build_x_lab(
    const float* __restrict__ lab_emb, const int* __restrict__ labels,
    unsigned short* __restrict__ x)
{
    int idx = blockIdx.x * 256 + threadIdx.x;   // 16384*32 total
    int np = idx >> 5, wd = idx & 31;
    int t = np >> 8, b = np & 255;
    int n = b * 64 + t;
    int prev = (t == 0) ? NLc : labels[n - 1];
    float2 lv = *(const float2*)&lab_emb[prev * 64 + wd * 2];
    ((unsigned*)(x + (size_t)np * 576 + 512))[wd] =
        (unsigned)f2bf(lv.x) | ((unsigned)f2bf(lv.y) << 16);
}

// ---------------------------------------------------------------------------
// gi GEMM (full 64 t): giT[3j+q][np] = bf16(sum_k Wgi.x + b), np = t*256+b.
// M=1536, N=16384, K=576. bf16 output halves store + GRU read traffic.
// ---------------------------------------------------------------------------
__global__ __launch_bounds__(256) void gi_gemm(
    const unsigned short* __restrict__ Wgi, const unsigned short* __restrict__ x,
    const float* __restrict__ gbihP, unsigned short* __restrict__ giT)
{
    __shared__ __align__(16) char smem[16384];
    const int n0 = blockIdx.x * 128;
    const int g0 = blockIdx.y * 128;
    const int tid = threadIdx.x;
    const int w = tid >> 6, l = tid & 63;
    const int wm = w & 1, wn = w >> 1;
    const int lrow = l & 15, lkb = (l >> 4) * 16;

    f32x4 acc[4][4];
    #pragma unroll
    for (int mf = 0; mf < 4; ++mf)
        #pragma unroll
        for (int nf = 0; nf < 4; ++nf)
            acc[mf][nf] = (f32x4){0.f, 0.f, 0.f, 0.f};

    for (int it = 0; it < 18; ++it) {
        const int k0 = it * 32;
        #pragma unroll
        for (int rr = 0; rr < 2; ++rr) {
            const int off = (rr * 4 + w) * 1024;
            const int row = (off + l * 16) >> 6;
            const int kb  = (off + l * 16) & 63;
            async16(smem + off,        (const char*)(Wgi + (size_t)(g0 + row) * 576 + k0) + kb);
            async16(smem + 8192 + off, (const char*)(x   + (size_t)(n0 + row) * 576 + k0) + kb);
        }
        __syncthreads();
        bf16x8 af[4], bfv[4];
        #pragma unroll
        for (int mf = 0; mf < 4; ++mf)
            af[mf] = *(const bf16x8*)(smem + ((wm * 64 + mf * 16 + lrow) * 64 + lkb));
        #pragma unroll
        for (int nf = 0; nf < 4; ++nf)
            bfv[nf] = *(const bf16x8*)(smem + 8192 + ((wn * 64 + nf * 16 + lrow) * 64 + lkb));
        #pragma unroll
        for (int mf = 0; mf < 4; ++mf)
            #pragma unroll
            for (int nf = 0; nf < 4; ++nf)
                acc[mf][nf] = __builtin_amdgcn_mfma_f32_16x16x32_bf16(af[mf], bfv[nf], acc[mf][nf], 0, 0, 0);
        __syncthreads();
    }
    #pragma unroll
    for (int mf = 0; mf < 4; ++mf) {
        const int rbase = g0 + wm * 64 + mf * 16 + (l >> 4) * 4;
        const float* bq = gbihP + rbase;
        #pragma unroll
        for (int nf = 0; nf < 4; ++nf) {
            const int np = n0 + wn * 64 + nf * 16 + lrow;
            #pragma unroll
            for (int reg = 0; reg < 4; ++reg)
                giT[(size_t)(rbase + reg) * 16384 + np] = f2bf(acc[mf][nf][reg] + bq[reg]);
        }
    }
}

// ---------------------------------------------------------------------------
// Persistent GRU v8: XCD-homed election (r17/r18-proven), ONE launch, all 64
// steps. 32 workers on ONE XCD -> one coherent L2 -> RELAXED flags, no
// fences. h state = 65-deep write-once/read-once chain. giT is bf16.
// ---------------------------------------------------------------------------
__global__ __launch_bounds__(512) void gru_persist(
    const unsigned short* __restrict__ Wg, const unsigned short* __restrict__ giT,
    const float* __restrict__ gbhhP, unsigned short* __restrict__ hb65,
    float* __restrict__ hsT, int* __restrict__ flags, int* __restrict__ elect)
{
    __shared__ __align__(16) unsigned short wl[64 * 520];   // 66.6 KB
    __shared__ int s_slot;
    const int tid = threadIdx.x;

    if (tid == 0) {
        int xcc = 0;
        asm volatile("s_getreg_b32 %0, hwreg(HW_REG_XCC_ID)" : "=s"(xcc));
        xcc &= 7;
        int pos = __hip_atomic_fetch_add(elect + xcc, 1, __ATOMIC_RELAXED,
                                         __HIP_MEMORY_SCOPE_AGENT);
        if (pos == 31) {                      // 32nd block of this XCD: claim
            int exp0 = 0;
            __hip_atomic_compare_exchange_strong(elect + 8, &exp0, xcc + 1,
                __ATOMIC_RELAXED, __ATOMIC_RELAXED, __HIP_MEMORY_SCOPE_AGENT);
        }
        int wres = 0; long cnt = 0;
        for (;;) {                            // wait for a winner (guaranteed)
            wres = __hip_atomic_load(elect + 8, __ATOMIC_RELAXED,
                                     __HIP_MEMORY_SCOPE_AGENT);
            if (wres != 0) break;
            if (++cnt > (1L << 24)) break;    // bailout: never hang
        }
        s_slot = (wres == xcc + 1 && pos < 32) ? pos : -1;
    }
    __syncthreads();
    const int slot = s_slot;
    if (slot < 0) return;                     // non-worker: exit, free the CU

    const int g0 = slot * 64;
    const int w = tid >> 6, l = tid & 63;
    const int lrow = l & 15, lhi = l >> 4;
    const int b0 = w * 32;

    for (int i = tid; i < 64 * 64; i += 512) {
        int r = i >> 6, c8 = i & 63;
        *(uint4*)&wl[r * 520 + c8 * 8] =
            *(const uint4*)&Wg[(size_t)(g0 + r) * 512 + c8 * 8];
    }
    __syncthreads();

    for (int t = 0; t < 64; ++t) {
        // prefetch gi for this step (h-independent) before the gate
        float gpre[4][2][3];
        #pragma unroll
        for (int mf = 0; mf < 4; ++mf) {
            const int j = (g0 + mf * 16 + lhi * 4) >> 2;
            #pragma unroll
            for (int bf = 0; bf < 2; ++bf) {
                const int col = t * 256 + b0 + bf * 16 + lrow;
                gpre[mf][bf][0] = bf2f(giT[(size_t)(3 * j + 0) * 16384 + col]);
                gpre[mf][bf][1] = bf2f(giT[(size_t)(3 * j + 1) * 16384 + col]);
                gpre[mf][bf][2] = bf2f(giT[(size_t)(3 * j + 2) * 16384 + col]);
            }
        }

        if (t > 0) {
            if (tid < 64) {                   // wave 0: RELAXED poll (L2-local)
                long cnt = 0;
                for (;;) {
                    int v = 1;
                    if (l < 32)
                        v = __hip_atomic_load(flags + (t - 1) * 32 + l,
                                              __ATOMIC_RELAXED, __HIP_MEMORY_SCOPE_AGENT);
                    if (__all(v != 0)) break;
                    if (++cnt > (1L << 24)) break;   // bailout: never hang
                }
            }
            __syncthreads();                  // all waves gated; same-L2, no fence
        }
        const unsigned short* hprev = hb65 + (size_t)t * 131072;    // fresh addr
        unsigned short* hnext = hb65 + (size_t)(t + 1) * 131072;

        f32x4 acc[4][2];
        #pragma unroll
        for (int mf = 0; mf < 4; ++mf) {
            acc[mf][0] = (f32x4){0.f, 0.f, 0.f, 0.f};
            acc[mf][1] = (f32x4){0.f, 0.f, 0.f, 0.f};
        }
        #pragma unroll
        for (int kc = 0; kc < 16; ++kc) {
            bf16x8 bfv[2];
            #pragma unroll
            for (int bf = 0; bf < 2; ++bf)
                bfv[bf] = *(const bf16x8*)(hprev + (size_t)(b0 + bf * 16 + lrow) * 512
                                                 + kc * 32 + lhi * 8);
            #pragma unroll
            for (int mf = 0; mf < 4; ++mf) {
                bf16x8 af = *(const bf16x8*)&wl[(mf * 16 + lrow) * 520 + kc * 32 + lhi * 8];
                acc[mf][0] = __builtin_amdgcn_mfma_f32_16x16x32_bf16(af, bfv[0], acc[mf][0], 0, 0, 0);
                acc[mf][1] = __builtin_amdgcn_mfma_f32_16x16x32_bf16(af, bfv[1], acc[mf][1], 0, 0, 0);
            }
        }

        const float* hsp = hsT + (size_t)t * 131072;
        float* hsn = hsT + (size_t)(t + 1) * 131072;
        #pragma unroll
        for (int mf = 0; mf < 4; ++mf) {
            const int grow = g0 + mf * 16 + lhi * 4;
            const int j = grow >> 2;
            float4 bq = *(const float4*)(gbhhP + grow);
            #pragma unroll
            for (int bf = 0; bf < 2; ++bf) {
                const int b = b0 + bf * 16 + lrow;
                float ghr = acc[mf][bf][0] + bq.x;
                float ghz = acc[mf][bf][1] + bq.y;
                float ghn = acc[mf][bf][2] + bq.z;
                float r = sigm(gpre[mf][bf][0] + ghr);
                float z = sigm(gpre[mf][bf][1] + ghz);
                float ng = ftanh(gpre[mf][bf][2] + r * ghn);
                float hp = hsp[j * 256 + b];
                float hn = (1.f - z) * ng + z * hp;
                hsn[j * 256 + b] = hn;
                hnext[(size_t)b * 512 + j] = f2bf(hn);
            }
        }
        __syncthreads();          // drains every wave's stores to L2
        if (tid == 0)
            __hip_atomic_store(flags + t * 32 + slot, 1,
                               __ATOMIC_RELAXED, __HIP_MEMORY_SCOPE_AGENT);
    }
}

// ---------------------------------------------------------------------------
// logits: block per t, 512 threads = (b, j-half); LDS partial reduce.
// ---------------------------------------------------------------------------
__global__ __launch_bounds__(512) void logits_k(
    const float* __restrict__ hsT, const float* __restrict__ Wout,
    const float* __restrict__ bout, float* __restrict__ out)
{
    __shared__ float red[2][256][17];   // 34.8 KB
    const int t = blockIdx.x;
    const int tid = threadIdx.x;
    const int b = tid & 255, js = tid >> 8;
    const float* h = hsT + (size_t)(t + 1) * 131072;
    float acc[17];
    #pragma unroll
    for (int l2 = 0; l2 < 17; ++l2) acc[l2] = 0.f;
    for (int j = js * 256; j < js * 256 + 256; ++j) {
        float hv = h[j * 256 + b];
        #pragma unroll
        for (int l2 = 0; l2 < 17; ++l2) acc[l2] += hv * Wout[l2 * 512 + j];
    }
    #pragma unroll
    for (int l2 = 0; l2 < 17; ++l2) red[js][b][l2] = acc[l2];
    __syncthreads();
    for (int o = tid; o < 256 * 17; o += 512) {
        int bb = o / 17, l2 = o - bb * 17;
        out[((size_t)bb * 64 + t) * 17 + l2] =
            red[0][bb][l2] + red[1][bb][l2] + bout[l2];
    }
}

} // namespace

extern "C" void kernel_launch(void* const* d_in, const int* in_sizes, int n_in,
                              void* d_out, int out_size, void* d_ws, size_t ws_size,
                              hipStream_t stream)
{
    const int*   tokens   = (const int*)d_in[0];
    const int*   seg_lens = (const int*)d_in[1];
    const int*   labels   = (const int*)d_in[2];
    const float* seg_emb  = (const float*)d_in[3];
    const float* Wih_f    = (const float*)d_in[4];
    const float* Whh_f    = (const float*)d_in[5];
    const float* bih_f    = (const float*)d_in[6];
    const float* bhh_f    = (const float*)d_in[7];
    const float* Wih_b    = (const float*)d_in[8];
    const float* Whh_b    = (const float*)d_in[9];
    const float* bih_b    = (const float*)d_in[10];
    const float* bhh_b    = (const float*)d_in[11];
    const float* lab_emb  = (const float*)d_in[12];
    const float* gWih     = (const float*)d_in[13];
    const float* gWhh     = (const float*)d_in[14];
    const float* gbih     = (const float*)d_in[15];
    const float* gbhh     = (const float*)d_in[16];
    const float* Wout     = (const float*)d_in[17];
    const float* bout     = (const float*)d_in[18];
    float* out = (float*)d_out;

    // Workspace ~122 MiB (bf16 giT 48 MiB covers all 64 steps).
    char* p = (char*)d_ws;
    auto take = [&](size_t bytes) { char* r = p; p += (bytes + 255) & ~size_t(255); return r; };
    unsigned short* Wl   = (unsigned short*)take((size_t)2 * 1024 * 256 * 2);    // Wl3 tiles
    float*          projP= (float*)take((size_t)2 * 3 * 1024 * 4);
    unsigned short* Wg   = (unsigned short*)take((size_t)2048 * 512 * 2);
    float*          gbhhP= (float*)take((size_t)2048 * 4);
    unsigned short* Wgi  = (unsigned short*)take((size_t)1536 * 576 * 2);
    float*          gbihP= (float*)take((size_t)1536 * 4);
    int*            flags= (int*)take((size_t)64 * 32 * sizeof(int));
    int*            elect= (int*)take((size_t)16 * sizeof(int));
    unsigned short* hb65 = (unsigned short*)take((size_t)65 * 131072 * 2);   // 16.3 MiB
    unsigned short* xbuf = (unsigned short*)take((size_t)16384 * 576 * 2);   // 18 MiB
    float*          hsT  = (float*)take((size_t)65 * 512 * 256 * 4);         // 32.5 MiB
    unsigned short* giT  = (unsigned short*)take((size_t)1536 * 16384 * 2);  // 48 MiB

    hipMemsetAsync(hb65, 0, (size_t)131072 * 2, stream);          // GRU h_0 (slot 0)
    hipMemsetAsync(hsT, 0, (size_t)512 * 256 * 4, stream);        // GRU h_{-1}=0 (f32)
    hipMemsetAsync(flags, 0, (size_t)64 * 32 * sizeof(int), stream);
    hipMemsetAsync(elect, 0, (size_t)16 * sizeof(int), stream);

    prep_lstm<<<264, 256, 0, stream>>>(Whh_f, Whh_b, Wih_f, bih_f, bhh_f,
                                       Wih_b, bih_b, bhh_b, seg_emb, Wl, projP);
    prep_gru<<<132, 256, 0, stream>>>(gWhh, gbhh, gWih, gbih, Wg, gbhhP, Wgi, gbihP);

    lstm_fused<<<dim3(256, 2), 512, 0, stream>>>(Wl, projP, tokens, seg_lens, xbuf);

    build_x_lab<<<2048, 256, 0, stream>>>(lab_emb, labels, xbuf);

    gi_gemm<<<dim3(128, 12), 256, 0, stream>>>(Wgi, xbuf, gbihP, giT);

    gru_persist<<<256, 512, 0, stream>>>(Wg, giT, gbhhP, hb65, hsT, flags, elect);

    logits_k<<<64, 512, 0, stream>>>(hsT, Wout, bout, out);
}

// Round 21
// 1067.980 us; speedup vs baseline: 2.2496x; 1.3204x over previous
//
#include <hip/hip_runtime.h>
#include <cmath>

namespace {
constexpr int NLc = 17;

typedef __attribute__((ext_vector_type(8))) short bf16x8;
typedef __attribute__((ext_vector_type(4))) float f32x4;

__device__ __forceinline__ float frcp(float x) { return __builtin_amdgcn_rcpf(x); }
__device__ __forceinline__ float sigm(float x) { return frcp(1.f + __expf(-x)); }
__device__ __forceinline__ float ftanh(float x) {
    float e = __expf(-2.f * fabsf(x));
    float t = (1.f - e) * frcp(1.f + e);
    return copysignf(t, x);
}

__device__ __forceinline__ unsigned short f2bf(float f) {
    union { float f; unsigned u; } v; v.f = f;
    unsigned r = v.u + 0x7FFF + ((v.u >> 16) & 1);
    return (unsigned short)(r >> 16);
}
__device__ __forceinline__ float bf2f(unsigned short s) {
    union { unsigned u; float f; } v; v.u = (unsigned)s << 16;
    return v.f;
}

// async global->LDS, 16B per lane; lds ptr must be wave-uniform (HW adds lane*16)
__device__ __forceinline__ void async16(void* lds_uniform, const void* gsrc) {
    __builtin_amdgcn_global_load_lds(
        (const __attribute__((address_space(1))) void*)gsrc,
        (__attribute__((address_space(3))) void*)lds_uniform,
        16, 0, 0);
}

// ---------------------------------------------------------------------------
// Prep: Wl3 = per-(GQ,kc,wave) 2KB tiles in LANE-LINEAR fragment order.
// ---------------------------------------------------------------------------
__global__ __launch_bounds__(256) void prep_lstm(
    const float* __restrict__ Whh_f, const float* __restrict__ Whh_b,
    const float* __restrict__ Wih_f, const float* __restrict__ bih_f, const float* __restrict__ bhh_f,
    const float* __restrict__ Wih_b, const float* __restrict__ bih_b, const float* __restrict__ bhh_b,
    const float* __restrict__ seg_emb,
    unsigned short* __restrict__ Wl3, float* __restrict__ projP)
{
    int idx = blockIdx.x * 256 + threadIdx.x;
    if (idx < 65536) {
        int dir = idx >> 15;
        int u = idx & 32767;
        int l  = u & 63;
        int mf = (u >> 6) & 1;
        int w  = (u >> 7) & 7;
        int kc = (u >> 10) & 7;
        int GQ = (u >> 13) & 3;
        const float* Whh = dir ? Whh_b : Whh_f;
        int g = GQ * 256 + w * 32 + mf * 16 + (l & 15);
        int q = g & 3, j = g >> 2;
        int k0 = kc * 32 + (l >> 4) * 8;
        const float* src = Whh + (size_t)(q * 256 + j) * 256 + k0;
        unsigned short* dst = Wl3 + (size_t)dir * 262144
                            + (size_t)((GQ * 8 + kc) * 8 + w) * 1024 + mf * 512 + l * 8;
        #pragma unroll
        for (int k = 0; k < 8; ++k) dst[k] = f2bf(src[k]);
    } else if (idx < 65536 + 2048) {
        int i2 = idx - 65536;
        int dir = i2 >> 10, gpp = i2 & 1023;
        int j = gpp >> 2, q = gpp & 3;
        const float* Wih = dir ? Wih_b : Wih_f;
        const float* bih = dir ? bih_b : bih_f;
        const float* bhh = dir ? bhh_b : bhh_f;
        int src = q * 256 + j;
        const float* wi = Wih + (size_t)src * 64;
        float bias = bih[src] + bhh[src];
        for (int tok = 0; tok < 3; ++tok) {
            float s = bias;
            for (int k = 0; k < 64; ++k) s += wi[k] * seg_emb[tok * 64 + k];
            projP[(dir * 3 + tok) * 1024 + gpp] = s;
        }
    }
}

// Wg[4j+q][k] (q==3 -> 0); gbhhP[4j+q]; Wgi[3j+q][k]; gbihP[3j+q]  (chunked)
__global__ __launch_bounds__(256) void prep_gru(
    const float* __restrict__ gWhh, const float* __restrict__ gbhh,
    const float* __restrict__ gWih, const float* __restrict__ gbih,
    unsigned short* __restrict__ Wg, float* __restrict__ gbhhP,
    unsigned short* __restrict__ Wgi, float* __restrict__ gbihP)
{
    int idx = blockIdx.x * 256 + threadIdx.x;
    if (idx < 16384) {                                  // Wg: 2048 rows x 8 chunks
        int row = idx >> 3, kc = idx & 7;
        int j = row >> 2, q = row & 3;
        unsigned short* dst = Wg + (size_t)row * 512 + kc * 64;
        if (q == 3) {
            #pragma unroll
            for (int k = 0; k < 64; ++k) dst[k] = 0;
        } else {
            const float* s = gWhh + (size_t)(q * 512 + j) * 512 + kc * 64;
            #pragma unroll
            for (int k = 0; k < 64; ++k) dst[k] = f2bf(s[k]);
        }
    } else if (idx < 16384 + 13824) {                   // Wgi: 1536 rows x 9 chunks
        int i2 = idx - 16384;
        int row = i2 / 9, kc = i2 - row * 9;
        int j = row / 3, q = row - j * 3;
        const float* s = gWih + (size_t)(q * 512 + j) * 576 + kc * 64;
        unsigned short* dst = Wgi + (size_t)row * 576 + kc * 64;
        #pragma unroll
        for (int k = 0; k < 64; ++k) dst[k] = f2bf(s[k]);
    } else if (idx < 16384 + 13824 + 2048) {            // gbhhP
        int row = idx - 16384 - 13824;
        int j = row >> 2, q = row & 3;
        gbhhP[row] = (q == 3) ? 0.f : gbhh[q * 512 + j];
    } else if (idx < 16384 + 13824 + 2048 + 1536) {     // gbihP
        int row = idx - 16384 - 13824 - 2048;
        int j = row / 3, q = row - j * 3;
        gbihP[row] = gbih[q * 512 + j];
    }
}

// ---------------------------------------------------------------------------
// One g''-quadrant of one LSTM step (r18-proven).
// ---------------------------------------------------------------------------
template<int GQ>
__device__ __forceinline__ void lstm_gq(
    const unsigned short* __restrict__ W,
    unsigned short* __restrict__ myring,
    const unsigned short* hcur, unsigned short* hnxt,
    const float* projL, const int* tl, const int (&len4)[4],
    int pos, int w, int lrow, int lhi, int l, float (&c)[2][4])
{
    f32x4 acc[2][4];
    #pragma unroll
    for (int mf = 0; mf < 2; ++mf)
        #pragma unroll
        for (int nf = 0; nf < 4; ++nf) acc[mf][nf] = (f32x4){0.f, 0.f, 0.f, 0.f};

    #pragma unroll
    for (int kc = 0; kc < 8; ++kc) {
        const int slot = kc & 3;
        asm volatile("s_waitcnt vmcnt(6)" ::: "memory");
        __builtin_amdgcn_sched_barrier(0);
        bf16x8 af0 = *(const bf16x8*)(myring + slot * 1024 + l * 8);
        bf16x8 af1 = *(const bf16x8*)(myring + slot * 1024 + 512 + l * 8);
        bf16x8 bfv[4];
        #pragma unroll
        for (int nf = 0; nf < 4; ++nf)
            bfv[nf] = *(const bf16x8*)&hcur[((nf * 8 + kc) * 64 + l) * 8];
        asm volatile("s_waitcnt lgkmcnt(0)" ::: "memory");
        __builtin_amdgcn_sched_barrier(0);
        {   const int nt = (GQ * 8 + kc + 4) & 31;
            const unsigned short* src = W + (size_t)(nt * 8 + w) * 1024 + l * 8;
            async16(myring + slot * 1024,       src);
            async16(myring + slot * 1024 + 512, src + 512);
        }
        #pragma unroll
        for (int nf = 0; nf < 4; ++nf) {
            acc[0][nf] = __builtin_amdgcn_mfma_f32_16x16x32_bf16(af0, bfv[nf], acc[0][nf], 0, 0, 0);
            acc[1][nf] = __builtin_amdgcn_mfma_f32_16x16x32_bf16(af1, bfv[nf], acc[1][nf], 0, 0, 0);
        }
    }

    #pragma unroll
    for (int nf = 0; nf < 4; ++nf) {
        const int base = ((nf * 8 + GQ * 2 + (w >> 2)) * 64 + (w & 3) * 16 + lrow) * 8;
        if (pos < len4[nf]) {
            const float* pr = projL + tl[pos * 64 + nf * 16 + lrow] * 1024;
            #pragma unroll
            for (int mf = 0; mf < 2; ++mf) {
                const int j = GQ * 64 + w * 8 + mf * 4 + lhi;
                float4 pv = *(const float4*)(pr + 4 * j);
                float gi_ = acc[mf][nf][0] + pv.x;
                float gf_ = acc[mf][nf][1] + pv.y;
                float gg_ = acc[mf][nf][2] + pv.z;
                float go_ = acc[mf][nf][3] + pv.w;
                float cn = sigm(gf_) * c[mf][nf] + sigm(gi_) * ftanh(gg_);
                c[mf][nf] = cn;
                hnxt[base + mf * 4 + lhi] = f2bf(sigm(go_) * ftanh(cn));
            }
        } else {
            #pragma unroll
            for (int mf = 0; mf < 2; ++mf)
                hnxt[base + mf * 4 + lhi] = hcur[base + mf * 4 + lhi];  // frozen
        }
    }
}

// ---------------------------------------------------------------------------
// Fully-fused LSTM; final h written directly into GRU input layout
// x[t*256 + b][dir*256 + j]  (r18-proven).
// ---------------------------------------------------------------------------
__global__ __launch_bounds__(512) void lstm_fused(
    const unsigned short* __restrict__ Wl3, const float* __restrict__ projP,
    const int* __restrict__ tokens, const int* __restrict__ seg_lens,
    unsigned short* __restrict__ xbuf)
{
    __shared__ __align__(16) unsigned short hl[2][16384];      // 64 KB
    __shared__ __align__(16) unsigned short wring[8][4 * 1024];// 64 KB
    __shared__ __align__(16) float projL[3072];                // 12 KB
    __shared__ int tl[1024];                                   // 4 KB [pos][nloc]
    const int dir = blockIdx.y;
    const int n0 = blockIdx.x * 64;
    const unsigned short* W = Wl3 + (size_t)dir * 262144;

    const int tid = threadIdx.x;
    const int w = tid >> 6, l = tid & 63;
    const int lrow = l & 15, lhi = l >> 4;

    for (int i = tid; i < 2048; i += 512)
        *(uint4*)&hl[0][i * 8] = make_uint4(0, 0, 0, 0);
    for (int i = tid; i < 1024; i += 512)
        tl[(i & 15) * 64 + (i >> 4)] = tokens[n0 * 16 + i];    // transpose-stage
    for (int i = tid; i < 3072; i += 512)
        projL[i] = projP[dir * 3072 + i];
    int len4[4];
    #pragma unroll
    for (int nf = 0; nf < 4; ++nf) len4[nf] = seg_lens[n0 + nf * 16 + lrow];
    __syncthreads();

    unsigned short* myring = wring[w];
    #pragma unroll
    for (int t = 0; t < 4; ++t) {
        const unsigned short* src = W + (size_t)(t * 8 + w) * 1024 + l * 8;
        async16(myring + t * 1024,       src);
        async16(myring + t * 1024 + 512, src + 512);
    }

    float c0[2][4] = {}, c1[2][4] = {}, c2[2][4] = {}, c3[2][4] = {};
    unsigned short* hcur = hl[0];
    unsigned short* hnxt = hl[1];
    for (int s = 0; s < 16; ++s) {
        const int pos = dir ? (15 - s) : s;
        lstm_gq<0>(W, myring, hcur, hnxt, projL, tl, len4, pos, w, lrow, lhi, l, c0);
        lstm_gq<1>(W, myring, hcur, hnxt, projL, tl, len4, pos, w, lrow, lhi, l, c1);
        lstm_gq<2>(W, myring, hcur, hnxt, projL, tl, len4, pos, w, lrow, lhi, l, c2);
        lstm_gq<3>(W, myring, hcur, hnxt, projL, tl, len4, pos, w, lrow, lhi, l, c3);
        __syncthreads();
        unsigned short* t2 = hcur; hcur = hnxt; hnxt = t2;
    }

    for (int i = tid; i < 2048; i += 512) {
        int row = i >> 5, chunk = i & 31;
        *(uint4*)&xbuf[((size_t)(row * 256 + blockIdx.x)) * 576 + dir * 256 + chunk * 8] =
            *(const uint4*)&hcur[(((row >> 4) * 8 + (chunk >> 2)) * 64
                                  + (chunk & 3) * 16 + (row & 15)) * 8];
    }
}

// ---------------------------------------------------------------------------
// build_x_lab: fill x[np][512..575] = bf16(lab_emb[prev]) only.
// ---------------------------------------------------------------------------
__global__ __launch_bounds__(256) void build_x_lab(
    const float* __restrict__ lab_emb, const int* __restrict__ labels,
    unsigned short* __restrict__ x)
{
    int idx = blockIdx.x * 256 + threadIdx.x;   // 16384*32 total
    int np = idx >> 5, wd = idx & 31;
    int t = np >> 8, b = np & 255;
    int n = b * 64 + t;
    int prev = (t == 0) ? NLc : labels[n - 1];
    float2 lv = *(const float2*)&lab_emb[prev * 64 + wd * 2];
    ((unsigned*)(x + (size_t)np * 576 + 512))[wd] =
        (unsigned)f2bf(lv.x) | ((unsigned)f2bf(lv.y) << 16);
}

// ---------------------------------------------------------------------------
// gi GEMM (full 64 t): giT[3j+q][np] = bf16(sum_k Wgi.x + b), np = t*256+b.
// ---------------------------------------------------------------------------
__global__ __launch_bounds__(256) void gi_gemm(
    const unsigned short* __restrict__ Wgi, const unsigned short* __restrict__ x,
    const float* __restrict__ gbihP, unsigned short* __restrict__ giT)
{
    __shared__ __align__(16) char smem[16384];
    const int n0 = blockIdx.x * 128;
    const int g0 = blockIdx.y * 128;
    const int tid = threadIdx.x;
    const int w = tid >> 6, l = tid & 63;
    const int wm = w & 1, wn = w >> 1;
    const int lrow = l & 15, lkb = (l >> 4) * 16;

    f32x4 acc[4][4];
    #pragma unroll
    for (int mf = 0; mf < 4; ++mf)
        #pragma unroll
        for (int nf = 0; nf < 4; ++nf)
            acc[mf][nf] = (f32x4){0.f, 0.f, 0.f, 0.f};

    for (int it = 0; it < 18; ++it) {
        const int k0 = it * 32;
        #pragma unroll
        for (int rr = 0; rr < 2; ++rr) {
            const int off = (rr * 4 + w) * 1024;
            const int row = (off + l * 16) >> 6;
            const int kb  = (off + l * 16) & 63;
            async16(smem + off,        (const char*)(Wgi + (size_t)(g0 + row) * 576 + k0) + kb);
            async16(smem + 8192 + off, (const char*)(x   + (size_t)(n0 + row) * 576 + k0) + kb);
        }
        __syncthreads();
        bf16x8 af[4], bfv[4];
        #pragma unroll
        for (int mf = 0; mf < 4; ++mf)
            af[mf] = *(const bf16x8*)(smem + ((wm * 64 + mf * 16 + lrow) * 64 + lkb));
        #pragma unroll
        for (int nf = 0; nf < 4; ++nf)
            bfv[nf] = *(const bf16x8*)(smem + 8192 + ((wn * 64 + nf * 16 + lrow) * 64 + lkb));
        #pragma unroll
        for (int mf = 0; mf < 4; ++mf)
            #pragma unroll
            for (int nf = 0; nf < 4; ++nf)
                acc[mf][nf] = __builtin_amdgcn_mfma_f32_16x16x32_bf16(af[mf], bfv[nf], acc[mf][nf], 0, 0, 0);
        __syncthreads();
    }
    #pragma unroll
    for (int mf = 0; mf < 4; ++mf) {
        const int rbase = g0 + wm * 64 + mf * 16 + (l >> 4) * 4;
        const float* bq = gbihP + rbase;
        #pragma unroll
        for (int nf = 0; nf < 4; ++nf) {
            const int np = n0 + wn * 64 + nf * 16 + lrow;
            #pragma unroll
            for (int reg = 0; reg < 4; ++reg)
                giT[(size_t)(rbase + reg) * 16384 + np] = f2bf(acc[mf][nf][reg] + bq[reg]);
        }
    }
}

// ---------------------------------------------------------------------------
// Persistent GRU v9: XCD-homed election, ONE launch, 64 steps.
// hb65 now FRAGMENT-LINEAR: [t][tile(bq,kc)][lane][8] where tile = bq*16+kc,
// lane = (b&15) + ((k>>3)&3)*16, elem = k&7  (bq = b>>4, kc = k>>5).
//   - reader (B-operand): 16B lane-linear coalesced loads
//   - writer: per-wave LDS transpose (stage) -> ONE coalesced 16B store
//     per thread (was 8 x 2B scatter at 1KB stride = 32x write amplification)
// hp (own h) kept in registers; hsT eliminated (logits reads hb65 bf16).
// ---------------------------------------------------------------------------
__global__ __launch_bounds__(512) void gru_persist(
    const unsigned short* __restrict__ Wg, const unsigned short* __restrict__ giT,
    const float* __restrict__ gbhhP, unsigned short* __restrict__ hb65,
    int* __restrict__ flags, int* __restrict__ elect)
{
    __shared__ __align__(16) unsigned short wl[64 * 520];   // 66.6 KB
    __shared__ __align__(16) unsigned short stage[8][512];  // 8 KB (1KB/wave)
    __shared__ int s_slot;
    const int tid = threadIdx.x;

    if (tid == 0) {
        int xcc = 0;
        asm volatile("s_getreg_b32 %0, hwreg(HW_REG_XCC_ID)" : "=s"(xcc));
        xcc &= 7;
        int pos = __hip_atomic_fetch_add(elect + xcc, 1, __ATOMIC_RELAXED,
                                         __HIP_MEMORY_SCOPE_AGENT);
        if (pos == 31) {                      // 32nd block of this XCD: claim
            int exp0 = 0;
            __hip_atomic_compare_exchange_strong(elect + 8, &exp0, xcc + 1,
                __ATOMIC_RELAXED, __ATOMIC_RELAXED, __HIP_MEMORY_SCOPE_AGENT);
        }
        int wres = 0; long cnt = 0;
        for (;;) {                            // wait for a winner (guaranteed)
            wres = __hip_atomic_load(elect + 8, __ATOMIC_RELAXED,
                                     __HIP_MEMORY_SCOPE_AGENT);
            if (wres != 0) break;
            if (++cnt > (1L << 24)) break;    // bailout: never hang
        }
        s_slot = (wres == xcc + 1 && pos < 32) ? pos : -1;
    }
    __syncthreads();
    const int slot = s_slot;
    if (slot < 0) return;                     // non-worker: exit, free the CU

    const int g0 = slot * 64;
    const int w = tid >> 6, l = tid & 63;
    const int lrow = l & 15, lhi = l >> 4;
    const int b0 = w * 32;

    for (int i = tid; i < 64 * 64; i += 512) {
        int r = i >> 6, c8 = i & 63;
        *(uint4*)&wl[r * 520 + c8 * 8] =
            *(const uint4*)&Wg[(size_t)(g0 + r) * 512 + c8 * 8];
    }
    __syncthreads();

    float hp[4][2] = {};   // own h (j = slot*16+mf*4+lhi, b = b0+bf*16+lrow)

    for (int t = 0; t < 64; ++t) {
        // prefetch gi for this step (h-independent) before the gate
        float gpre[4][2][3];
        #pragma unroll
        for (int mf = 0; mf < 4; ++mf) {
            const int j = (g0 + mf * 16 + lhi * 4) >> 2;
            #pragma unroll
            for (int bf = 0; bf < 2; ++bf) {
                const int col = t * 256 + b0 + bf * 16 + lrow;
                gpre[mf][bf][0] = bf2f(giT[(size_t)(3 * j + 0) * 16384 + col]);
                gpre[mf][bf][1] = bf2f(giT[(size_t)(3 * j + 1) * 16384 + col]);
                gpre[mf][bf][2] = bf2f(giT[(size_t)(3 * j + 2) * 16384 + col]);
            }
        }

        if (t > 0) {
            if (tid < 64) {                   // wave 0: RELAXED poll (L2-local)
                long cnt = 0;
                for (;;) {
                    int v = 1;
                    if (l < 32)
                        v = __hip_atomic_load(flags + (t - 1) * 32 + l,
                                              __ATOMIC_RELAXED, __HIP_MEMORY_SCOPE_AGENT);
                    if (__all(v != 0)) break;
                    if (++cnt > (1L << 24)) break;   // bailout: never hang
                }
            }
            __syncthreads();                  // all waves gated; same-L2, no fence
        }
        const unsigned short* hprev = hb65 + (size_t)t * 131072;    // fresh addr
        unsigned short* hnext = hb65 + (size_t)(t + 1) * 131072;

        f32x4 acc[4][2];
        #pragma unroll
        for (int mf = 0; mf < 4; ++mf) {
            acc[mf][0] = (f32x4){0.f, 0.f, 0.f, 0.f};
            acc[mf][1] = (f32x4){0.f, 0.f, 0.f, 0.f};
        }
        #pragma unroll
        for (int kc = 0; kc < 16; ++kc) {
            bf16x8 bfv[2];
            #pragma unroll
            for (int bf = 0; bf < 2; ++bf)
                bfv[bf] = *(const bf16x8*)(hprev
                            + (size_t)(((w * 2 + bf) * 16 + kc) * 64 + l) * 8);
            #pragma unroll
            for (int mf = 0; mf < 4; ++mf) {
                bf16x8 af = *(const bf16x8*)&wl[(mf * 16 + lrow) * 520 + kc * 32 + lhi * 8];
                acc[mf][0] = __builtin_amdgcn_mfma_f32_16x16x32_bf16(af, bfv[0], acc[mf][0], 0, 0, 0);
                acc[mf][1] = __builtin_amdgcn_mfma_f32_16x16x32_bf16(af, bfv[1], acc[mf][1], 0, 0, 0);
            }
        }

        // cell update (hp in regs) + stage own h into LDS [b&31][k&15]
        #pragma unroll
        for (int mf = 0; mf < 4; ++mf) {
            const int grow = g0 + mf * 16 + lhi * 4;
            float4 bq = *(const float4*)(gbhhP + grow);
            #pragma unroll
            for (int bf = 0; bf < 2; ++bf) {
                float r = sigm(gpre[mf][bf][0] + acc[mf][bf][0] + bq.x);
                float z = sigm(gpre[mf][bf][1] + acc[mf][bf][1] + bq.y);
                float ng = ftanh(gpre[mf][bf][2] + r * (acc[mf][bf][2] + bq.z));
                float hn = (1.f - z) * ng + z * hp[mf][bf];
                hp[mf][bf] = hn;
                stage[w][(bf * 16 + lrow) * 16 + mf * 4 + lhi] = f2bf(hn);
            }
        }
        asm volatile("s_waitcnt lgkmcnt(0)" ::: "memory");   // wave-local transpose done
        __builtin_amdgcn_sched_barrier(0);
        {   // fragment-linear store: one coalesced 16B per thread
            const int half = (l >> 4) & 1;            // (k&15)>>3
            const int bq   = w * 2 + (l >> 5);
            const int srow = (l & 15) + ((l >> 5) << 4);
            const int lhi2 = (slot & 1) * 2 + half;   // (k>>3)&3
            const int tile = bq * 16 + (slot >> 1);   // kc = slot>>1
            bf16x8 v = *(const bf16x8*)&stage[w][srow * 16 + half * 8];
            *(bf16x8*)&hnext[(size_t)(tile * 64 + (l & 15) + lhi2 * 16) * 8] = v;
        }
        __syncthreads();          // drains every wave's stores to L2
        if (tid == 0)
            __hip_atomic_store(flags + t * 32 + slot, 1,
                               __ATOMIC_RELAXED, __HIP_MEMORY_SCOPE_AGENT);
    }
}

// ---------------------------------------------------------------------------
// logits: block per t, 512 threads = (b, k-half); reads bf16 hb65 fragment
// layout; LDS partial reduce.
// ---------------------------------------------------------------------------
__global__ __launch_bounds__(512) void logits_k(
    const unsigned short* __restrict__ hb65, const float* __restrict__ Wout,
    const float* __restrict__ bout, float* __restrict__ out)
{
    __shared__ float red[2][256][17];   // 34.8 KB
    const int t = blockIdx.x;
    const int tid = threadIdx.x;
    const int b = tid & 255, js = tid >> 8;
    const unsigned short* h = hb65 + (size_t)(t + 1) * 131072;
    float acc[17];
    #pragma unroll
    for (int l2 = 0; l2 < 17; ++l2) acc[l2] = 0.f;
    for (int kc = js * 8; kc < js * 8 + 8; ++kc) {
        #pragma unroll
        for (int lh = 0; lh < 4; ++lh) {
            bf16x8 hv8 = *(const bf16x8*)&h[
                (size_t)((((b >> 4) * 16 + kc) * 64 + (b & 15) + lh * 16)) * 8];
            #pragma unroll
            for (int e = 0; e < 8; ++e) {
                float hv = bf2f((unsigned short)hv8[e]);
                const int k = kc * 32 + lh * 8 + e;
                #pragma unroll
                for (int l2 = 0; l2 < 17; ++l2) acc[l2] += hv * Wout[l2 * 512 + k];
            }
        }
    }
    #pragma unroll
    for (int l2 = 0; l2 < 17; ++l2) red[js][b][l2] = acc[l2];
    __syncthreads();
    for (int o = tid; o < 256 * 17; o += 512) {
        int bb = o / 17, l2 = o - bb * 17;
        out[((size_t)bb * 64 + t) * 17 + l2] =
            red[0][bb][l2] + red[1][bb][l2] + bout[l2];
    }
}

} // namespace

extern "C" void kernel_launch(void* const* d_in, const int* in_sizes, int n_in,
                              void* d_out, int out_size, void* d_ws, size_t ws_size,
                              hipStream_t stream)
{
    const int*   tokens   = (const int*)d_in[0];
    const int*   seg_lens = (const int*)d_in[1];
    const int*   labels   = (const int*)d_in[2];
    const float* seg_emb  = (const float*)d_in[3];
    const float* Wih_f    = (const float*)d_in[4];
    const float* Whh_f    = (const float*)d_in[5];
    const float* bih_f    = (const float*)d_in[6];
    const float* bhh_f    = (const float*)d_in[7];
    const float* Wih_b    = (const float*)d_in[8];
    const float* Whh_b    = (const float*)d_in[9];
    const float* bih_b    = (const float*)d_in[10];
    const float* bhh_b    = (const float*)d_in[11];
    const float* lab_emb  = (const float*)d_in[12];
    const float* gWih     = (const float*)d_in[13];
    const float* gWhh     = (const float*)d_in[14];
    const float* gbih     = (const float*)d_in[15];
    const float* gbhh     = (const float*)d_in[16];
    const float* Wout     = (const float*)d_in[17];
    const float* bout     = (const float*)d_in[18];
    float* out = (float*)d_out;

    // Workspace ~90 MiB (hsT eliminated).
    char* p = (char*)d_ws;
    auto take = [&](size_t bytes) { char* r = p; p += (bytes + 255) & ~size_t(255); return r; };
    unsigned short* Wl   = (unsigned short*)take((size_t)2 * 1024 * 256 * 2);    // Wl3 tiles
    float*          projP= (float*)take((size_t)2 * 3 * 1024 * 4);
    unsigned short* Wg   = (unsigned short*)take((size_t)2048 * 512 * 2);
    float*          gbhhP= (float*)take((size_t)2048 * 4);
    unsigned short* Wgi  = (unsigned short*)take((size_t)1536 * 576 * 2);
    float*          gbihP= (float*)take((size_t)1536 * 4);
    int*            flags= (int*)take((size_t)64 * 32 * sizeof(int));
    int*            elect= (int*)take((size_t)16 * sizeof(int));
    unsigned short* hb65 = (unsigned short*)take((size_t)65 * 131072 * 2);   // 16.3 MiB
    unsigned short* xbuf = (unsigned short*)take((size_t)16384 * 576 * 2);   // 18 MiB
    unsigned short* giT  = (unsigned short*)take((size_t)1536 * 16384 * 2);  // 48 MiB

    hipMemsetAsync(hb65, 0, (size_t)131072 * 2, stream);          // GRU h_0 (slot 0)
    hipMemsetAsync(flags, 0, (size_t)64 * 32 * sizeof(int), stream);
    hipMemsetAsync(elect, 0, (size_t)16 * sizeof(int), stream);

    prep_lstm<<<264, 256, 0, stream>>>(Whh_f, Whh_b, Wih_f, bih_f, bhh_f,
                                       Wih_b, bih_b, bhh_b, seg_emb, Wl, projP);
    prep_gru<<<132, 256, 0, stream>>>(gWhh, gbhh, gWih, gbih, Wg, gbhhP, Wgi, gbihP);

    lstm_fused<<<dim3(256, 2), 512, 0, stream>>>(Wl, projP, tokens, seg_lens, xbuf);

    build_x_lab<<<2048, 256, 0, stream>>>(lab_emb, labels, xbuf);

    gi_gemm<<<dim3(128, 12), 256, 0, stream>>>(Wgi, xbuf, gbihP, giT);

    gru_persist<<<256, 512, 0, stream>>>(Wg, giT, gbhhP, hb65, flags, elect);

    logits_k<<<64, 512, 0, stream>>>(hb65, Wout, bout, out);
}